// Round 2
// baseline (1309.240 us; speedup 1.0000x reference)
//
#include <hip/hip_runtime.h>
#include <cstddef>
#include <cstdint>

typedef _Float16 f16;
typedef __attribute__((ext_vector_type(4))) _Float16 half4;
typedef __attribute__((ext_vector_type(8))) _Float16 half8;
typedef __attribute__((ext_vector_type(4))) float floatx4;

#define TSEQ 2048
#define DMODEL 2048
#define LDQKV 3072
#define NHEADS 16
#define NKVH 4
#define HD 128
#define INTERDIM 5632
#define LDGU 11264

typedef const __attribute__((address_space(1))) void gvoid_t;
typedef __attribute__((address_space(3))) void svoid_t;
#define GLOAD_LDS(g, s) __builtin_amdgcn_global_load_lds((gvoid_t*)(g), (svoid_t*)(s), 16, 0, 0)

// ---------------- fp32 -> fp16 cast ----------------
__global__ __launch_bounds__(256) void cast_kernel(const float* __restrict__ in,
                                                   f16* __restrict__ out, int n4) {
    int i = blockIdx.x * 256 + threadIdx.x;
    if (i >= n4) return;
    float4 v = ((const float4*)in)[i];
    half4 o;
    o.x = (f16)v.x; o.y = (f16)v.y; o.z = (f16)v.z; o.w = (f16)v.w;
    ((half4*)out)[i] = o;
}

// ---------------- RMSNorm (fp32 in, fp16 out), row = 2048 ----------------
__global__ __launch_bounds__(256) void rmsnorm_kernel(const float* __restrict__ x,
                                                      const float* __restrict__ w,
                                                      f16* __restrict__ out) {
    int row = blockIdx.x;
    const float* xr = x + (size_t)row * DMODEL;
    int base = threadIdx.x * 8;
    float4 a = *(const float4*)(xr + base);
    float4 b = *(const float4*)(xr + base + 4);
    float ss = a.x*a.x + a.y*a.y + a.z*a.z + a.w*a.w
             + b.x*b.x + b.y*b.y + b.z*b.z + b.w*b.w;
#pragma unroll
    for (int off = 32; off >= 1; off >>= 1) ss += __shfl_xor(ss, off, 64);
    __shared__ float part[4];
    if ((threadIdx.x & 63) == 0) part[threadIdx.x >> 6] = ss;
    __syncthreads();
    float tot = part[0] + part[1] + part[2] + part[3];
    float inv = rsqrtf(tot * (1.0f / DMODEL) + 1e-6f);
    const float* wr = w + base;
    half8 o;
    o[0] = (f16)(a.x * inv * wr[0]);
    o[1] = (f16)(a.y * inv * wr[1]);
    o[2] = (f16)(a.z * inv * wr[2]);
    o[3] = (f16)(a.w * inv * wr[3]);
    o[4] = (f16)(b.x * inv * wr[4]);
    o[5] = (f16)(b.y * inv * wr[5]);
    o[6] = (f16)(b.z * inv * wr[6]);
    o[7] = (f16)(b.w * inv * wr[7]);
    *(half8*)(out + (size_t)row * DMODEL + base) = o;
}

// ---------------- GEMM: C[M,N] = A[M,K] @ B[N,K]^T, m97 structure ----------
// 128x128 tile, BK=32, 256 threads (4 waves 2x2), global_load_lds width-16.
__global__ __launch_bounds__(256) void gemm_bt(const f16* __restrict__ A, int lda,
                                               const f16* __restrict__ B, int ldb,
                                               f16* __restrict__ Ch, float* __restrict__ Cf,
                                               const float* __restrict__ res,
                                               int ldc, int K) {
    const int col0 = blockIdx.x * 128, row0 = blockIdx.y * 128;
    const int t = threadIdx.x;
    const int w = t >> 6, lane = t & 63, cl = lane & 15, quad = lane >> 4;
    const int wm = (w >> 1) * 64, wn = (w & 1) * 64;
    __shared__ __align__(16) f16 As[128 * 32];
    __shared__ __align__(16) f16 Bs[128 * 32];

    // staging: wave w covers rows [w*16, w*16+16) and [64+w*16, 64+w*16+16)
    const int srow = w * 16 + (lane >> 2);
    const int scol = (lane & 3) * 8;
    const f16* gA0 = A + (size_t)(row0 + srow) * lda + scol;
    const f16* gA1 = A + (size_t)(row0 + 64 + srow) * lda + scol;
    const f16* gB0 = B + (size_t)(col0 + srow) * ldb + scol;
    const f16* gB1 = B + (size_t)(col0 + 64 + srow) * ldb + scol;
    f16* sA0 = &As[w * 512];
    f16* sA1 = &As[2048 + w * 512];
    f16* sB0 = &Bs[w * 512];
    f16* sB1 = &Bs[2048 + w * 512];

    const f16* fa[4];
    const f16* fb[4];
#pragma unroll
    for (int mt = 0; mt < 4; ++mt) {
        fa[mt] = &As[(wm + mt * 16 + cl) * 32 + quad * 8];
        fb[mt] = &Bs[(wn + mt * 16 + cl) * 32 + quad * 8];
    }

    const floatx4 fzero = {0.f, 0.f, 0.f, 0.f};
    floatx4 acc[4][4];
#pragma unroll
    for (int mt = 0; mt < 4; ++mt)
#pragma unroll
        for (int nt = 0; nt < 4; ++nt) acc[mt][nt] = fzero;

    for (int k0 = 0; k0 < K; k0 += 32) {
        __syncthreads();
        GLOAD_LDS(gA0 + k0, sA0);
        GLOAD_LDS(gA1 + k0, sA1);
        GLOAD_LDS(gB0 + k0, sB0);
        GLOAD_LDS(gB1 + k0, sB1);
        __syncthreads();
        half8 av[4], bv[4];
#pragma unroll
        for (int mt = 0; mt < 4; ++mt) av[mt] = *(const half8*)fa[mt];
#pragma unroll
        for (int nt = 0; nt < 4; ++nt) bv[nt] = *(const half8*)fb[nt];
#pragma unroll
        for (int mt = 0; mt < 4; ++mt)
#pragma unroll
            for (int nt = 0; nt < 4; ++nt)
                acc[mt][nt] = __builtin_amdgcn_mfma_f32_16x16x32_f16(av[mt], bv[nt],
                                                                     acc[mt][nt], 0, 0, 0);
    }

#pragma unroll
    for (int mt = 0; mt < 4; ++mt)
#pragma unroll
        for (int nt = 0; nt < 4; ++nt)
#pragma unroll
            for (int r = 0; r < 4; ++r) {
                int grow = row0 + wm + mt * 16 + quad * 4 + r;
                int gcol = col0 + wn + nt * 16 + cl;
                size_t idx = (size_t)grow * ldc + gcol;
                float v = acc[mt][nt][r];
                if (Cf) Cf[idx] = res[idx] + v;
                else    Ch[idx] = (f16)v;
            }
}

// ---------------- RoPE (in-place on q and k columns of qkv) ----------------
__global__ __launch_bounds__(256) void rope_kernel(f16* __restrict__ qkv) {
    int idx = blockIdx.x * 256 + threadIdx.x;  // 4096 * 1280
    int row = idx / 1280;
    int p = idx - row * 1280;
    int t = row & (TSEQ - 1);
    int colbase, i;
    if (p < 1024) { colbase = (p >> 6) * 128; i = p & 63; }
    else { int pp = p - 1024; colbase = 2048 + (pp >> 6) * 128; i = pp & 63; }
    float inv = expf((float)i * -0.14391156831f);  // ln(10000)/64
    float ang = (float)t * inv;
    float s, c;
    sincosf(ang, &s, &c);
    size_t base = (size_t)row * LDQKV + colbase;
    float x1 = (float)qkv[base + i];
    float x2 = (float)qkv[base + 64 + i];
    qkv[base + i]      = (f16)(x1 * c - x2 * s);
    qkv[base + 64 + i] = (f16)(x2 * c + x1 * s);
}

// ---------------- transpose V: (b,t,kvh,d) -> vt[(b,kvh,d), t] ----------------
__global__ __launch_bounds__(256) void transpose_v(const f16* __restrict__ qkv,
                                                   f16* __restrict__ vt) {
    int z = blockIdx.z;  // b*4 + kvh
    int b = z >> 2, kvh = z & 3;
    int t0 = blockIdx.x * 32, d0 = blockIdx.y * 32;
    __shared__ f16 tile[32][33];
    const f16* src = qkv + (size_t)(b * TSEQ + t0) * LDQKV + 2560 + kvh * HD + d0;
    for (int i = threadIdx.y; i < 32; i += 8)
        tile[i][threadIdx.x] = src[(size_t)i * LDQKV + threadIdx.x];
    __syncthreads();
    f16* dst = vt + (size_t)(z * HD + d0) * TSEQ + t0;
    for (int i = threadIdx.y; i < 32; i += 8)
        dst[(size_t)i * TSEQ + threadIdx.x] = tile[threadIdx.x][i];
}

// ---------------- flash attention v2: 4 independent waves/block ------------
// Each wave: 32 q-rows, K-chunks of 64, 64 MFMAs per chunk, no barriers.
__global__ __launch_bounds__(256) void flash_attn(const f16* __restrict__ qkv,
                                                  const f16* __restrict__ vt,
                                                  f16* __restrict__ out) {
    const int w = threadIdx.x >> 6, lane = threadIdx.x & 63;
    const int cl = lane & 15, quad = lane >> 4;
    const int q0 = blockIdx.x * 128 + w * 32;
    const int h = blockIdx.y, b = blockIdx.z;
    const int kvh = h >> 2;
    const f16* Q  = qkv + (size_t)b * TSEQ * LDQKV + h * HD;
    const f16* Kp = qkv + (size_t)b * TSEQ * LDQKV + DMODEL + kvh * HD;
    const f16* Vt = vt + (size_t)(b * NKVH + kvh) * HD * TSEQ;

    half8 qf[2][4];
#pragma unroll
    for (int mt = 0; mt < 2; ++mt)
#pragma unroll
        for (int ks = 0; ks < 4; ++ks)
            qf[mt][ks] = *(const half8*)(Q + (size_t)(q0 + mt * 16 + cl) * LDQKV
                                         + ks * 32 + quad * 8);

    float m_[8], l_[8];
#pragma unroll
    for (int i = 0; i < 8; ++i) { m_[i] = -1e30f; l_[i] = 0.f; }
    const floatx4 fzero = {0.f, 0.f, 0.f, 0.f};
    floatx4 o[2][8];
#pragma unroll
    for (int mt = 0; mt < 2; ++mt)
#pragma unroll
        for (int nt = 0; nt < 8; ++nt) o[mt][nt] = fzero;

    __shared__ __align__(16) f16 Psh[4][32 * 64];
    f16* P = Psh[w];

    // fold 1/sqrt(128) and log2(e) into the score scale (exp2 domain)
    const float scale = 0.088388347648318447f * 1.4426950408889634f;

    const int nfull   = (q0 + 1)  >> 6;   // fully-unmasked 64-chunks
    const int nchunks = (q0 + 95) >> 6;   // total 64-chunks

    for (int c = 0; c < nchunks; ++c) {
        const int kb = c * 64;
        const bool masked = (c >= nfull);

        floatx4 s[2][4];
#pragma unroll
        for (int mt = 0; mt < 2; ++mt)
#pragma unroll
            for (int nt = 0; nt < 4; ++nt) s[mt][nt] = fzero;
#pragma unroll
        for (int ks = 0; ks < 4; ++ks) {
            half8 kf[4];
#pragma unroll
            for (int nt = 0; nt < 4; ++nt)
                kf[nt] = *(const half8*)(Kp + (size_t)(kb + nt * 16 + cl) * LDQKV
                                         + ks * 32 + quad * 8);
#pragma unroll
            for (int mt = 0; mt < 2; ++mt)
#pragma unroll
                for (int nt = 0; nt < 4; ++nt)
                    s[mt][nt] = __builtin_amdgcn_mfma_f32_16x16x32_f16(qf[mt][ks], kf[nt],
                                                                       s[mt][nt], 0, 0, 0);
        }

#pragma unroll
        for (int mt = 0; mt < 2; ++mt)
#pragma unroll
            for (int r = 0; r < 4; ++r) {
                const int i8 = mt * 4 + r;
                const int row = q0 + mt * 16 + quad * 4 + r;
                float v[4];
#pragma unroll
                for (int nt = 0; nt < 4; ++nt) {
                    v[nt] = s[mt][nt][r] * scale;
                    if (masked) {
                        int col = kb + nt * 16 + cl;
                        if (col > row) v[nt] = -1e30f;
                    }
                }
                float mx = fmaxf(fmaxf(v[0], v[1]), fmaxf(v[2], v[3]));
#pragma unroll
                for (int off = 1; off < 16; off <<= 1) mx = fmaxf(mx, __shfl_xor(mx, off, 64));
                float mnew = fmaxf(m_[i8], mx);
                float alpha = exp2f(m_[i8] - mnew);
                float p[4];
#pragma unroll
                for (int nt = 0; nt < 4; ++nt) p[nt] = exp2f(v[nt] - mnew);
                float rs = (p[0] + p[1]) + (p[2] + p[3]);
#pragma unroll
                for (int off = 1; off < 16; off <<= 1) rs += __shfl_xor(rs, off, 64);
                l_[i8] = l_[i8] * alpha + rs;
                m_[i8] = mnew;
#pragma unroll
                for (int nt = 0; nt < 8; ++nt) o[mt][nt][r] *= alpha;
                const int pr = mt * 16 + quad * 4 + r;
#pragma unroll
                for (int nt = 0; nt < 4; ++nt) {
                    int col = nt * 16 + cl;
                    int cs = ((((col >> 3) ^ (pr & 7)) << 3) | (col & 7));
                    P[pr * 64 + cs] = (f16)p[nt];
                }
            }

#pragma unroll
        for (int kk = 0; kk < 2; ++kk) {
            half8 pf[2];
#pragma unroll
            for (int mt = 0; mt < 2; ++mt) {
                int pr = mt * 16 + cl;
                int cb = kk * 4 + quad;
                pf[mt] = *(const half8*)&P[pr * 64 + ((cb ^ (pr & 7)) << 3)];
            }
#pragma unroll
            for (int nt = 0; nt < 8; ++nt) {
                half8 vv = *(const half8*)(Vt + (size_t)(nt * 16 + cl) * TSEQ
                                           + kb + kk * 32 + quad * 8);
#pragma unroll
                for (int mt = 0; mt < 2; ++mt)
                    o[mt][nt] = __builtin_amdgcn_mfma_f32_16x16x32_f16(pf[mt], vv,
                                                                       o[mt][nt], 0, 0, 0);
            }
        }
    }

    f16* Op = out + (size_t)(b * TSEQ + q0) * DMODEL + h * HD;
#pragma unroll
    for (int mt = 0; mt < 2; ++mt)
#pragma unroll
        for (int r = 0; r < 4; ++r) {
            float invl = 1.0f / l_[mt * 4 + r];
#pragma unroll
            for (int nt = 0; nt < 8; ++nt)
                Op[(size_t)(mt * 16 + quad * 4 + r) * DMODEL + nt * 16 + cl] =
                    (f16)(o[mt][nt][r] * invl);
        }
}

// ---------------- SwiGLU: gu[:, :5632] = silu(gate) * up (in place) ---------
__global__ __launch_bounds__(256) void silu_mul(f16* __restrict__ gu) {
    int idx = blockIdx.x * 256 + threadIdx.x;  // 4096 * 704
    int row = idx / 704;
    int j = (idx - row * 704) * 8;
    size_t base = (size_t)row * LDGU;
    half8 g = *(half8*)(gu + base + j);
    half8 u = *(half8*)(gu + base + INTERDIM + j);
    half8 o;
#pragma unroll
    for (int e = 0; e < 8; ++e) {
        float gv = (float)g[e], uv = (float)u[e];
        float sg = gv / (1.f + __expf(-gv));
        o[e] = (f16)(sg * uv);
    }
    *(half8*)(gu + base + j) = o;
}

extern "C" void kernel_launch(void* const* d_in, const int* in_sizes, int n_in,
                              void* d_out, int out_size, void* d_ws, size_t ws_size,
                              hipStream_t stream) {
    const float* x   = (const float*)d_in[0];
    const float* ln1 = (const float*)d_in[1];
    const float* ln2 = (const float*)d_in[2];
    const float* wq  = (const float*)d_in[3];
    const float* wk  = (const float*)d_in[4];
    const float* wv  = (const float*)d_in[5];
    const float* wo  = (const float*)d_in[6];
    const float* wg  = (const float*)d_in[7];
    const float* wu  = (const float*)d_in[8];
    const float* wd  = (const float*)d_in[9];
    float* out = (float*)d_out;

    char* p = (char*)d_ws;
    f16* wqkv_h = (f16*)p; p += (size_t)3072 * 2048 * 2;
    f16* wo_h   = (f16*)p; p += (size_t)2048 * 2048 * 2;
    f16* wgu_h  = (f16*)p; p += (size_t)11264 * 2048 * 2;
    f16* wd_h   = (f16*)p; p += (size_t)2048 * 5632 * 2;
    f16* h_h    = (f16*)p; p += (size_t)4096 * 2048 * 2;  // later reused as attn-out
    f16* qkv_h  = (f16*)p; p += (size_t)4096 * 3072 * 2;  // later reused as h2
    f16* vt_h   = (f16*)p; p += (size_t)8 * 128 * 2048 * 2;
    f16* gu_h   = (f16*)p;                                 // 4096*11264*2

    auto cast = [&](const float* src, f16* dst, size_t n) {
        int n4 = (int)(n / 4);
        cast_kernel<<<(n4 + 255) / 256, 256, 0, stream>>>(src, dst, n4);
    };
    cast(wq, wqkv_h,                       (size_t)2048 * 2048);
    cast(wk, wqkv_h + (size_t)2048 * 2048, (size_t)512 * 2048);
    cast(wv, wqkv_h + (size_t)2560 * 2048, (size_t)512 * 2048);
    cast(wo, wo_h,                         (size_t)2048 * 2048);
    cast(wg, wgu_h,                        (size_t)5632 * 2048);
    cast(wu, wgu_h + (size_t)5632 * 2048,  (size_t)5632 * 2048);
    cast(wd, wd_h,                         (size_t)2048 * 5632);

    rmsnorm_kernel<<<4096, 256, 0, stream>>>(x, ln1, h_h);
    // QKV projection (fused N = 2048+512+512 = 3072)
    gemm_bt<<<dim3(24, 32), 256, 0, stream>>>(h_h, 2048, wqkv_h, 2048,
                                              qkv_h, nullptr, nullptr, 3072, 2048);
    rope_kernel<<<20480, 256, 0, stream>>>(qkv_h);
    transpose_v<<<dim3(64, 4, 8), dim3(32, 8), 0, stream>>>(qkv_h, vt_h);
    flash_attn<<<dim3(16, 16, 2), 256, 0, stream>>>(qkv_h, vt_h, h_h);
    // out = x + attn @ wo^T   (fp32 residual into d_out)
    gemm_bt<<<dim3(16, 32), 256, 0, stream>>>(h_h, 2048, wo_h, 2048,
                                              nullptr, out, x, 2048, 2048);
    rmsnorm_kernel<<<4096, 256, 0, stream>>>(out, ln2, qkv_h);  // h2 in qkv buffer
    // gate|up (fused N = 11264)
    gemm_bt<<<dim3(88, 32), 256, 0, stream>>>(qkv_h, 2048, wgu_h, 2048,
                                              gu_h, nullptr, nullptr, 11264, 2048);
    silu_mul<<<11264, 256, 0, stream>>>(gu_h);
    // out += mid @ wd^T
    gemm_bt<<<dim3(16, 32), 256, 0, stream>>>(gu_h, 11264, wd_h, 5632,
                                              nullptr, out, out, 2048, 5632);
}

// Round 3
// 998.320 us; speedup vs baseline: 1.3114x; 1.3114x over previous
//
#include <hip/hip_runtime.h>
#include <cstddef>
#include <cstdint>

typedef _Float16 f16;
typedef __attribute__((ext_vector_type(4))) _Float16 half4;
typedef __attribute__((ext_vector_type(8))) _Float16 half8;
typedef __attribute__((ext_vector_type(4))) float floatx4;

#define TSEQ 2048
#define DMODEL 2048
#define LDQKV 3072
#define NHEADS 16
#define NKVH 4
#define HD 128
#define INTERDIM 5632
#define LDGU 11264

typedef const __attribute__((address_space(1))) void gvoid_t;
typedef __attribute__((address_space(3))) void svoid_t;
#define GLOAD_LDS(g, s) __builtin_amdgcn_global_load_lds((gvoid_t*)(g), (svoid_t*)(s), 16, 0, 0)

// ---------------- fp32 -> fp16 cast ----------------
__global__ __launch_bounds__(256) void cast_kernel(const float* __restrict__ in,
                                                   f16* __restrict__ out, int n4) {
    int i = blockIdx.x * 256 + threadIdx.x;
    if (i >= n4) return;
    float4 v = ((const float4*)in)[i];
    half4 o;
    o.x = (f16)v.x; o.y = (f16)v.y; o.z = (f16)v.z; o.w = (f16)v.w;
    ((half4*)out)[i] = o;
}

// ---------------- RMSNorm (fp32 in, fp16 out), row = 2048 ----------------
__global__ __launch_bounds__(256) void rmsnorm_kernel(const float* __restrict__ x,
                                                      const float* __restrict__ w,
                                                      f16* __restrict__ out) {
    int row = blockIdx.x;
    const float* xr = x + (size_t)row * DMODEL;
    int base = threadIdx.x * 8;
    float4 a = *(const float4*)(xr + base);
    float4 b = *(const float4*)(xr + base + 4);
    float ss = a.x*a.x + a.y*a.y + a.z*a.z + a.w*a.w
             + b.x*b.x + b.y*b.y + b.z*b.z + b.w*b.w;
#pragma unroll
    for (int off = 32; off >= 1; off >>= 1) ss += __shfl_xor(ss, off, 64);
    __shared__ float part[4];
    if ((threadIdx.x & 63) == 0) part[threadIdx.x >> 6] = ss;
    __syncthreads();
    float tot = part[0] + part[1] + part[2] + part[3];
    float inv = rsqrtf(tot * (1.0f / DMODEL) + 1e-6f);
    const float* wr = w + base;
    half8 o;
    o[0] = (f16)(a.x * inv * wr[0]);
    o[1] = (f16)(a.y * inv * wr[1]);
    o[2] = (f16)(a.z * inv * wr[2]);
    o[3] = (f16)(a.w * inv * wr[3]);
    o[4] = (f16)(b.x * inv * wr[4]);
    o[5] = (f16)(b.y * inv * wr[5]);
    o[6] = (f16)(b.z * inv * wr[6]);
    o[7] = (f16)(b.w * inv * wr[7]);
    *(half8*)(out + (size_t)row * DMODEL + base) = o;
}

// ---------------- GEMM: C[M,N] = A[M,K] @ B[N,K]^T, dbuf global_load_lds ----
__global__ __launch_bounds__(256) void gemm_bt(const f16* __restrict__ A, int lda,
                                               const f16* __restrict__ B, int ldb,
                                               f16* __restrict__ Ch, float* __restrict__ Cf,
                                               const float* __restrict__ res,
                                               int ldc, int K) {
    const int col0 = blockIdx.x * 128, row0 = blockIdx.y * 128;
    const int t = threadIdx.x;
    const int w = t >> 6, lane = t & 63, cl = lane & 15, quad = lane >> 4;
    const int wm = (w >> 1) * 64, wn = (w & 1) * 64;
    __shared__ __align__(16) f16 As[2][128 * 32];
    __shared__ __align__(16) f16 Bs[2][128 * 32];

    const int srow = w * 16 + (lane >> 2);
    const int scol = (lane & 3) * 8;
    const f16* gA0 = A + (size_t)(row0 + srow) * lda + scol;
    const f16* gA1 = A + (size_t)(row0 + 64 + srow) * lda + scol;
    const f16* gB0 = B + (size_t)(col0 + srow) * ldb + scol;
    const f16* gB1 = B + (size_t)(col0 + 64 + srow) * ldb + scol;
    const int so0 = w * 512;
    const int so1 = 2048 + w * 512;

    int fao[4], fbo[4];
#pragma unroll
    for (int mt = 0; mt < 4; ++mt) {
        fao[mt] = (wm + mt * 16 + cl) * 32 + quad * 8;
        fbo[mt] = (wn + mt * 16 + cl) * 32 + quad * 8;
    }

    const floatx4 fzero = {0.f, 0.f, 0.f, 0.f};
    floatx4 acc[4][4];
#pragma unroll
    for (int mt = 0; mt < 4; ++mt)
#pragma unroll
        for (int nt = 0; nt < 4; ++nt) acc[mt][nt] = fzero;

    GLOAD_LDS(gA0, As[0] + so0);
    GLOAD_LDS(gA1, As[0] + so1);
    GLOAD_LDS(gB0, Bs[0] + so0);
    GLOAD_LDS(gB1, Bs[0] + so1);
    __syncthreads();

    for (int k0 = 0; k0 < K; k0 += 32) {
        const int buf = (k0 >> 5) & 1;
        const int kn = k0 + 32;
        if (kn < K) {
            GLOAD_LDS(gA0 + kn, As[buf ^ 1] + so0);
            GLOAD_LDS(gA1 + kn, As[buf ^ 1] + so1);
            GLOAD_LDS(gB0 + kn, Bs[buf ^ 1] + so0);
            GLOAD_LDS(gB1 + kn, Bs[buf ^ 1] + so1);
        }
        const f16* Ab = As[buf];
        const f16* Bb = Bs[buf];
        half8 av[4], bv[4];
#pragma unroll
        for (int mt = 0; mt < 4; ++mt) av[mt] = *(const half8*)(Ab + fao[mt]);
#pragma unroll
        for (int nt = 0; nt < 4; ++nt) bv[nt] = *(const half8*)(Bb + fbo[nt]);
#pragma unroll
        for (int mt = 0; mt < 4; ++mt)
#pragma unroll
            for (int nt = 0; nt < 4; ++nt)
                acc[mt][nt] = __builtin_amdgcn_mfma_f32_16x16x32_f16(av[mt], bv[nt],
                                                                     acc[mt][nt], 0, 0, 0);
        __syncthreads();
    }

#pragma unroll
    for (int mt = 0; mt < 4; ++mt)
#pragma unroll
        for (int nt = 0; nt < 4; ++nt)
#pragma unroll
            for (int r = 0; r < 4; ++r) {
                int grow = row0 + wm + mt * 16 + quad * 4 + r;
                int gcol = col0 + wn + nt * 16 + cl;
                size_t idx = (size_t)grow * ldc + gcol;
                float v = acc[mt][nt][r];
                if (Cf) Cf[idx] = res[idx] + v;
                else    Ch[idx] = (f16)v;
            }
}

// ---------------- RoPE on q columns (in place) ----------------
__global__ __launch_bounds__(256) void rope_q(f16* __restrict__ qkv) {
    int idx = blockIdx.x * 256 + threadIdx.x;   // 4096*16*64
    int i = idx & 63;
    int hh = (idx >> 6) & 15;
    int row = idx >> 10;
    int t = row & (TSEQ - 1);
    f16* base = qkv + (size_t)row * LDQKV + hh * HD;
    float inv = __expf((float)i * -0.14391156831f);  // ln(10000)/64
    float ang = (float)t * inv;
    float s, c;
    sincosf(ang, &s, &c);
    float x1 = (float)base[i], x2 = (float)base[i + 64];
    base[i]      = (f16)(x1 * c - x2 * s);
    base[i + 64] = (f16)(x2 * c + x1 * s);
}

// ------------- K repack: rope + swizzled [z][t][128] contiguous -------------
// 16B-block j of row t stored at j ^ (t&15).
__global__ __launch_bounds__(256) void repack_k(const f16* __restrict__ qkv,
                                                f16* __restrict__ kpack) {
    int idx = blockIdx.x * 256 + threadIdx.x;   // 4096*4*64
    int i = idx & 63;
    int kvh = (idx >> 6) & 3;
    int row = idx >> 8;
    int t = row & (TSEQ - 1);
    int b = row >> 11;
    const f16* src = qkv + (size_t)row * LDQKV + DMODEL + kvh * HD;
    float inv = __expf((float)i * -0.14391156831f);
    float ang = (float)t * inv;
    float s, c;
    sincosf(ang, &s, &c);
    float x1 = (float)src[i], x2 = (float)src[i + 64];
    float r1 = x1 * c - x2 * s, r2 = x2 * c + x1 * s;
    f16* dst = kpack + ((size_t)((b * NKVH + kvh) * TSEQ + t)) * HD;
    int sw = t & 15;
    int i2 = i + 64;
    dst[(((i  >> 3) ^ sw) << 3) + (i  & 7)] = (f16)r1;
    dst[(((i2 >> 3) ^ sw) << 3) + (i2 & 7)] = (f16)r2;
}

// ------- V repack: [z][chunk][d][64] tiles (16 KB contiguous), swizzled -----
// 16B-block j (of 8) in d-row stored at j ^ (d&7).
__global__ __launch_bounds__(256) void repack_v(const f16* __restrict__ qkv,
                                                f16* __restrict__ vpack) {
    int z = blockIdx.x >> 5;
    int c = blockIdx.x & 31;
    int b = z >> 2, kvh = z & 3;
    __shared__ f16 tile[64][136];
    int tr = threadIdx.x >> 4;
    int tcol = (threadIdx.x & 15) * 8;
    const f16* src = qkv + (size_t)(b * TSEQ + c * 64) * LDQKV + 2560 + kvh * HD;
#pragma unroll
    for (int i = 0; i < 4; ++i) {
        int row = i * 16 + tr;
        *(half8*)&tile[row][tcol] = *(const half8*)(src + (size_t)row * LDQKV + tcol);
    }
    __syncthreads();
    int d = threadIdx.x >> 1, hf = threadIdx.x & 1;
    f16* dst = vpack + ((size_t)z * 32 + c) * 8192 + d * 64;
#pragma unroll
    for (int j8 = 0; j8 < 4; ++j8) {
        int blk = hf * 4 + j8;
        half8 v;
#pragma unroll
        for (int e = 0; e < 8; ++e) v[e] = tile[blk * 8 + e][d];
        *(half8*)(dst + ((blk ^ (d & 7)) << 3)) = v;
    }
}

// ---------------- flash attention v3: LDS-staged, double-buffered -----------
__global__ __launch_bounds__(256) void flash_attn(const f16* __restrict__ qkv,
                                                  const f16* __restrict__ kpack,
                                                  const f16* __restrict__ vpack,
                                                  f16* __restrict__ out) {
    const int L = blockIdx.x;
    const int tt = L & 255;
    const int h = tt >> 4;
    const int qi = tt & 15;
    const int b = L >> 8;
    const int qt = b ? qi : (15 - qi);   // LPT pairing: L and L+256 complement
    const int q0 = qt * 128;
    const int w = threadIdx.x >> 6, lane = threadIdx.x & 63;
    const int cl = lane & 15, quad = lane >> 4;
    const int kvh = h >> 2;
    const int z = b * NKVH + kvh;
    const int qw = q0 + w * 32;

    __shared__ __align__(16) f16 Ks[2][64 * 128];
    __shared__ __align__(16) f16 Vs[2][64 * 128];
    __shared__ __align__(16) f16 Psh[4][32 * 64];
    f16* P = Psh[w];

    const f16* Q  = qkv + (size_t)(b * TSEQ) * LDQKV + h * HD;
    const f16* Kg = kpack + (size_t)z * (TSEQ * HD);
    const f16* Vg = vpack + (size_t)z * (32 * 8192);

    half8 qf[2][4];
#pragma unroll
    for (int mt = 0; mt < 2; ++mt)
#pragma unroll
        for (int ks = 0; ks < 4; ++ks)
            qf[mt][ks] = *(const half8*)(Q + (size_t)(qw + mt * 16 + cl) * LDQKV
                                         + ks * 32 + quad * 8);

    float m_[8], l_[8];
#pragma unroll
    for (int i = 0; i < 8; ++i) { m_[i] = -1e30f; l_[i] = 0.f; }
    const floatx4 fzero = {0.f, 0.f, 0.f, 0.f};
    floatx4 o[2][8];
#pragma unroll
    for (int mt = 0; mt < 2; ++mt)
#pragma unroll
        for (int nt = 0; nt < 8; ++nt) o[mt][nt] = fzero;

    const float scale = 0.088388347648318447f * 1.4426950408889634f;
    const int nblk   = ((q0 + 127) >> 6) + 1;
    const int nfullw = (qw + 1) >> 6;
    const int nstopw = ((qw + 31) >> 6) + 1;

    const int po = w * 512 + lane * 8;   // per-lane element offset for staging
    const int bo = w * 512;              // wave-uniform LDS element offset

#pragma unroll
    for (int r = 0; r < 4; ++r) {
        GLOAD_LDS(Kg + r * 2048 + po, Ks[0] + r * 2048 + bo);
        GLOAD_LDS(Vg + r * 2048 + po, Vs[0] + r * 2048 + bo);
    }
    __syncthreads();

    for (int c = 0; c < nblk; ++c) {
        const int buf = c & 1;
        if (c + 1 < nblk) {
            const f16* gk = Kg + (size_t)(c + 1) * 8192;
            const f16* gv = Vg + (size_t)(c + 1) * 8192;
            f16* sk = Ks[buf ^ 1];
            f16* sv = Vs[buf ^ 1];
#pragma unroll
            for (int r = 0; r < 4; ++r) {
                GLOAD_LDS(gk + r * 2048 + po, sk + r * 2048 + bo);
                GLOAD_LDS(gv + r * 2048 + po, sv + r * 2048 + bo);
            }
        }
        if (c < nstopw) {
            const int kb = c * 64;
            const bool masked = (c >= nfullw);
            const f16* KL = Ks[buf];
            const f16* VL = Vs[buf];

            floatx4 s[2][4];
#pragma unroll
            for (int mt = 0; mt < 2; ++mt)
#pragma unroll
                for (int nt = 0; nt < 4; ++nt) s[mt][nt] = fzero;
#pragma unroll
            for (int ks = 0; ks < 4; ++ks) {
                half8 kf[4];
#pragma unroll
                for (int nt = 0; nt < 4; ++nt) {
                    int r = nt * 16 + cl;
                    kf[nt] = *(const half8*)&KL[r * 128 + (((ks * 4 + quad) ^ (r & 15)) << 3)];
                }
#pragma unroll
                for (int mt = 0; mt < 2; ++mt)
#pragma unroll
                    for (int nt = 0; nt < 4; ++nt)
                        s[mt][nt] = __builtin_amdgcn_mfma_f32_16x16x32_f16(qf[mt][ks], kf[nt],
                                                                           s[mt][nt], 0, 0, 0);
            }

#pragma unroll
            for (int mt = 0; mt < 2; ++mt)
#pragma unroll
                for (int r = 0; r < 4; ++r) {
                    const int i8 = mt * 4 + r;
                    const int row = qw + mt * 16 + quad * 4 + r;
                    float v[4];
#pragma unroll
                    for (int nt = 0; nt < 4; ++nt) {
                        v[nt] = s[mt][nt][r] * scale;
                        if (masked) {
                            int col = kb + nt * 16 + cl;
                            if (col > row) v[nt] = -1e30f;
                        }
                    }
                    float mx = fmaxf(fmaxf(v[0], v[1]), fmaxf(v[2], v[3]));
#pragma unroll
                    for (int off = 1; off < 16; off <<= 1) mx = fmaxf(mx, __shfl_xor(mx, off, 64));
                    float mnew = fmaxf(m_[i8], mx);
                    float alpha = exp2f(m_[i8] - mnew);
                    float p[4];
#pragma unroll
                    for (int nt = 0; nt < 4; ++nt) p[nt] = exp2f(v[nt] - mnew);
                    float rs = (p[0] + p[1]) + (p[2] + p[3]);
#pragma unroll
                    for (int off = 1; off < 16; off <<= 1) rs += __shfl_xor(rs, off, 64);
                    l_[i8] = l_[i8] * alpha + rs;
                    m_[i8] = mnew;
#pragma unroll
                    for (int nt = 0; nt < 8; ++nt) o[mt][nt][r] *= alpha;
                    const int pr = mt * 16 + quad * 4 + r;
#pragma unroll
                    for (int nt = 0; nt < 4; ++nt) {
                        int col = nt * 16 + cl;
                        int cs = ((((col >> 3) ^ (pr & 7)) << 3) | (col & 7));
                        P[pr * 64 + cs] = (f16)p[nt];
                    }
                }

#pragma unroll
            for (int kk = 0; kk < 2; ++kk) {
                half8 pf[2];
#pragma unroll
                for (int mt = 0; mt < 2; ++mt) {
                    int pr = mt * 16 + cl;
                    int cb = kk * 4 + quad;
                    pf[mt] = *(const half8*)&P[pr * 64 + ((cb ^ (pr & 7)) << 3)];
                }
#pragma unroll
                for (int nt = 0; nt < 8; ++nt) {
                    int r = nt * 16 + cl;
                    half8 vv = *(const half8*)&VL[r * 64 + (((kk * 4 + quad) ^ (r & 7)) << 3)];
#pragma unroll
                    for (int mt = 0; mt < 2; ++mt)
                        o[mt][nt] = __builtin_amdgcn_mfma_f32_16x16x32_f16(pf[mt], vv,
                                                                           o[mt][nt], 0, 0, 0);
                }
            }
        }
        __syncthreads();
    }

    f16* Op = out + (size_t)(b * TSEQ + qw) * DMODEL + h * HD;
#pragma unroll
    for (int mt = 0; mt < 2; ++mt)
#pragma unroll
        for (int r = 0; r < 4; ++r) {
            float invl = 1.0f / l_[mt * 4 + r];
#pragma unroll
            for (int nt = 0; nt < 8; ++nt)
                Op[(size_t)(mt * 16 + quad * 4 + r) * DMODEL + nt * 16 + cl] =
                    (f16)(o[mt][nt][r] * invl);
        }
}

// ---------------- SwiGLU: gu[:, :5632] = silu(gate) * up (in place) ---------
__global__ __launch_bounds__(256) void silu_mul(f16* __restrict__ gu) {
    int idx = blockIdx.x * 256 + threadIdx.x;  // 4096 * 704
    int row = idx / 704;
    int j = (idx - row * 704) * 8;
    size_t base = (size_t)row * LDGU;
    half8 g = *(half8*)(gu + base + j);
    half8 u = *(half8*)(gu + base + INTERDIM + j);
    half8 o;
#pragma unroll
    for (int e = 0; e < 8; ++e) {
        float gv = (float)g[e], uv = (float)u[e];
        float sg = gv / (1.f + __expf(-gv));
        o[e] = (f16)(sg * uv);
    }
    *(half8*)(gu + base + j) = o;
}

extern "C" void kernel_launch(void* const* d_in, const int* in_sizes, int n_in,
                              void* d_out, int out_size, void* d_ws, size_t ws_size,
                              hipStream_t stream) {
    const float* x   = (const float*)d_in[0];
    const float* ln1 = (const float*)d_in[1];
    const float* ln2 = (const float*)d_in[2];
    const float* wq  = (const float*)d_in[3];
    const float* wk  = (const float*)d_in[4];
    const float* wv  = (const float*)d_in[5];
    const float* wo  = (const float*)d_in[6];
    const float* wg  = (const float*)d_in[7];
    const float* wu  = (const float*)d_in[8];
    const float* wd  = (const float*)d_in[9];
    float* out = (float*)d_out;

    char* p = (char*)d_ws;
    f16* wqkv_h = (f16*)p; p += (size_t)3072 * 2048 * 2;
    f16* wo_h   = (f16*)p; p += (size_t)2048 * 2048 * 2;
    f16* wgu_h  = (f16*)p; p += (size_t)11264 * 2048 * 2;
    f16* wd_h   = (f16*)p; p += (size_t)2048 * 5632 * 2;
    f16* h_h    = (f16*)p; p += (size_t)4096 * 2048 * 2;  // later reused as attn-out
    f16* qkv_h  = (f16*)p; p += (size_t)4096 * 3072 * 2;  // later reused as h2
    f16* kpack  = (f16*)p; p += (size_t)8 * 2048 * 128 * 2;
    f16* vpack  = (f16*)p; p += (size_t)8 * 32 * 8192 * 2;
    f16* gu_h   = (f16*)p;                                 // 4096*11264*2

    auto cast = [&](const float* src, f16* dst, size_t n) {
        int n4 = (int)(n / 4);
        cast_kernel<<<(n4 + 255) / 256, 256, 0, stream>>>(src, dst, n4);
    };
    cast(wq, wqkv_h,                       (size_t)2048 * 2048);
    cast(wk, wqkv_h + (size_t)2048 * 2048, (size_t)512 * 2048);
    cast(wv, wqkv_h + (size_t)2560 * 2048, (size_t)512 * 2048);
    cast(wo, wo_h,                         (size_t)2048 * 2048);
    cast(wg, wgu_h,                        (size_t)5632 * 2048);
    cast(wu, wgu_h + (size_t)5632 * 2048,  (size_t)5632 * 2048);
    cast(wd, wd_h,                         (size_t)2048 * 5632);

    rmsnorm_kernel<<<4096, 256, 0, stream>>>(x, ln1, h_h);
    // QKV projection (fused N = 2048+512+512 = 3072)
    gemm_bt<<<dim3(24, 32), 256, 0, stream>>>(h_h, 2048, wqkv_h, 2048,
                                              qkv_h, nullptr, nullptr, 3072, 2048);
    rope_q<<<16384, 256, 0, stream>>>(qkv_h);
    repack_k<<<4096, 256, 0, stream>>>(qkv_h, kpack);
    repack_v<<<256, 256, 0, stream>>>(qkv_h, vpack);
    flash_attn<<<512, 256, 0, stream>>>(qkv_h, kpack, vpack, h_h);
    // out = x + attn @ wo^T   (fp32 residual into d_out)
    gemm_bt<<<dim3(16, 32), 256, 0, stream>>>(h_h, 2048, wo_h, 2048,
                                              nullptr, out, x, 2048, 2048);
    rmsnorm_kernel<<<4096, 256, 0, stream>>>(out, ln2, qkv_h);  // h2 in qkv buffer
    // gate|up (fused N = 11264)
    gemm_bt<<<dim3(88, 32), 256, 0, stream>>>(qkv_h, 2048, wgu_h, 2048,
                                              gu_h, nullptr, nullptr, 11264, 2048);
    silu_mul<<<11264, 256, 0, stream>>>(gu_h);
    // out += mid @ wd^T
    gemm_bt<<<dim3(16, 32), 256, 0, stream>>>(gu_h, 11264, wd_h, 5632,
                                              nullptr, out, out, 2048, 5632);
}

// Round 4
// 975.590 us; speedup vs baseline: 1.3420x; 1.0233x over previous
//
#include <hip/hip_runtime.h>
#include <cstddef>
#include <cstdint>

typedef _Float16 f16;
typedef __attribute__((ext_vector_type(4))) _Float16 half4;
typedef __attribute__((ext_vector_type(8))) _Float16 half8;
typedef __attribute__((ext_vector_type(4))) float floatx4;

#define TSEQ 2048
#define DMODEL 2048
#define LDQKV 3072
#define NHEADS 16
#define NKVH 4
#define HD 128
#define INTERDIM 5632
#define LDGU 11264

typedef const __attribute__((address_space(1))) void gvoid_t;
typedef __attribute__((address_space(3))) void svoid_t;
#define GLOAD_LDS(g, s) __builtin_amdgcn_global_load_lds((gvoid_t*)(g), (svoid_t*)(s), 16, 0, 0)

// ------------- fused fp32 -> fp16 cast of all 7 weight regions --------------
// Region table in 256-float4 blocks:
//   wq 4096 | wk 1024 | wv 1024 | wo 4096 | wg 11264 | wu 11264 | wd 11264
__global__ __launch_bounds__(256) void cast_all(const float* __restrict__ wq,
                                                const float* __restrict__ wk,
                                                const float* __restrict__ wv,
                                                const float* __restrict__ wo,
                                                const float* __restrict__ wg,
                                                const float* __restrict__ wu,
                                                const float* __restrict__ wd,
                                                f16* __restrict__ wqkv_h,
                                                f16* __restrict__ wo_h,
                                                f16* __restrict__ wgu_h,
                                                f16* __restrict__ wd_h) {
    int b = blockIdx.x;
    const float* s;
    f16* d;
    int rb;
    if (b < 4096)       { s = wq; d = wqkv_h;                        rb = b; }
    else if (b < 5120)  { s = wk; d = wqkv_h + (size_t)2048 * 2048;  rb = b - 4096; }
    else if (b < 6144)  { s = wv; d = wqkv_h + (size_t)2560 * 2048;  rb = b - 5120; }
    else if (b < 10240) { s = wo; d = wo_h;                          rb = b - 6144; }
    else if (b < 21504) { s = wg; d = wgu_h;                         rb = b - 10240; }
    else if (b < 32768) { s = wu; d = wgu_h + (size_t)5632 * 2048;   rb = b - 21504; }
    else                { s = wd; d = wd_h;                          rb = b - 32768; }
    size_t i = (size_t)rb * 256 + threadIdx.x;
    float4 v = ((const float4*)s)[i];
    half4 o;
    o.x = (f16)v.x; o.y = (f16)v.y; o.z = (f16)v.z; o.w = (f16)v.w;
    ((half4*)d)[i] = o;
}

// ---------------- RMSNorm (fp32 in, fp16 out), row = 2048 ----------------
__global__ __launch_bounds__(256) void rmsnorm_kernel(const float* __restrict__ x,
                                                      const float* __restrict__ w,
                                                      f16* __restrict__ out) {
    int row = blockIdx.x;
    const float* xr = x + (size_t)row * DMODEL;
    int base = threadIdx.x * 8;
    float4 a = *(const float4*)(xr + base);
    float4 b = *(const float4*)(xr + base + 4);
    float ss = a.x*a.x + a.y*a.y + a.z*a.z + a.w*a.w
             + b.x*b.x + b.y*b.y + b.z*b.z + b.w*b.w;
#pragma unroll
    for (int off = 32; off >= 1; off >>= 1) ss += __shfl_xor(ss, off, 64);
    __shared__ float part[4];
    if ((threadIdx.x & 63) == 0) part[threadIdx.x >> 6] = ss;
    __syncthreads();
    float tot = part[0] + part[1] + part[2] + part[3];
    float inv = rsqrtf(tot * (1.0f / DMODEL) + 1e-6f);
    const float* wr = w + base;
    half8 o;
    o[0] = (f16)(a.x * inv * wr[0]);
    o[1] = (f16)(a.y * inv * wr[1]);
    o[2] = (f16)(a.z * inv * wr[2]);
    o[3] = (f16)(a.w * inv * wr[3]);
    o[4] = (f16)(b.x * inv * wr[4]);
    o[5] = (f16)(b.y * inv * wr[5]);
    o[6] = (f16)(b.z * inv * wr[6]);
    o[7] = (f16)(b.w * inv * wr[7]);
    *(half8*)(out + (size_t)row * DMODEL + base) = o;
}

// ---------------- GEMM: C[M,N] = A[M,K] @ B[N,K]^T, dbuf global_load_lds ----
// 1-D grid with 16-row supertile swizzle: 256 consecutive blocks cover a
// 16x16 block region (8 MB A + 8 MB B) for L2/L3 reuse.
__global__ __launch_bounds__(256) void gemm_bt(const f16* __restrict__ A, int lda,
                                               const f16* __restrict__ B, int ldb,
                                               f16* __restrict__ Ch, float* __restrict__ Cf,
                                               const float* __restrict__ res,
                                               int ldc, int K, int nbx) {
    const int bid = blockIdx.x;
    const int per = nbx << 4;
    const int grp = bid / per;
    const int rem = bid - grp * per;
    const int bx = rem >> 4;
    const int by = (grp << 4) + (rem & 15);
    const int col0 = bx * 128, row0 = by * 128;

    const int t = threadIdx.x;
    const int w = t >> 6, lane = t & 63, cl = lane & 15, quad = lane >> 4;
    const int wm = (w >> 1) * 64, wn = (w & 1) * 64;
    __shared__ __align__(16) f16 As[2][128 * 32];
    __shared__ __align__(16) f16 Bs[2][128 * 32];

    const int srow = w * 16 + (lane >> 2);
    const int scol = (lane & 3) * 8;
    const f16* gA0 = A + (size_t)(row0 + srow) * lda + scol;
    const f16* gA1 = A + (size_t)(row0 + 64 + srow) * lda + scol;
    const f16* gB0 = B + (size_t)(col0 + srow) * ldb + scol;
    const f16* gB1 = B + (size_t)(col0 + 64 + srow) * ldb + scol;
    const int so0 = w * 512;
    const int so1 = 2048 + w * 512;

    int fao[4], fbo[4];
#pragma unroll
    for (int mt = 0; mt < 4; ++mt) {
        fao[mt] = (wm + mt * 16 + cl) * 32 + quad * 8;
        fbo[mt] = (wn + mt * 16 + cl) * 32 + quad * 8;
    }

    const floatx4 fzero = {0.f, 0.f, 0.f, 0.f};
    floatx4 acc[4][4];
#pragma unroll
    for (int mt = 0; mt < 4; ++mt)
#pragma unroll
        for (int nt = 0; nt < 4; ++nt) acc[mt][nt] = fzero;

    GLOAD_LDS(gA0, As[0] + so0);
    GLOAD_LDS(gA1, As[0] + so1);
    GLOAD_LDS(gB0, Bs[0] + so0);
    GLOAD_LDS(gB1, Bs[0] + so1);
    __syncthreads();

    for (int k0 = 0; k0 < K; k0 += 32) {
        const int buf = (k0 >> 5) & 1;
        const int kn = k0 + 32;
        if (kn < K) {
            GLOAD_LDS(gA0 + kn, As[buf ^ 1] + so0);
            GLOAD_LDS(gA1 + kn, As[buf ^ 1] + so1);
            GLOAD_LDS(gB0 + kn, Bs[buf ^ 1] + so0);
            GLOAD_LDS(gB1 + kn, Bs[buf ^ 1] + so1);
        }
        const f16* Ab = As[buf];
        const f16* Bb = Bs[buf];
        half8 av[4], bv[4];
#pragma unroll
        for (int mt = 0; mt < 4; ++mt) av[mt] = *(const half8*)(Ab + fao[mt]);
#pragma unroll
        for (int nt = 0; nt < 4; ++nt) bv[nt] = *(const half8*)(Bb + fbo[nt]);
#pragma unroll
        for (int mt = 0; mt < 4; ++mt)
#pragma unroll
            for (int nt = 0; nt < 4; ++nt)
                acc[mt][nt] = __builtin_amdgcn_mfma_f32_16x16x32_f16(av[mt], bv[nt],
                                                                     acc[mt][nt], 0, 0, 0);
        __syncthreads();
    }

#pragma unroll
    for (int mt = 0; mt < 4; ++mt)
#pragma unroll
        for (int nt = 0; nt < 4; ++nt)
#pragma unroll
            for (int r = 0; r < 4; ++r) {
                int grow = row0 + wm + mt * 16 + quad * 4 + r;
                int gcol = col0 + wn + nt * 16 + cl;
                size_t idx = (size_t)grow * ldc + gcol;
                float v = acc[mt][nt][r];
                if (Cf) Cf[idx] = res[idx] + v;
                else    Ch[idx] = (f16)v;
            }
}

// ---------------- RoPE on q columns (in place) ----------------
__global__ __launch_bounds__(256) void rope_q(f16* __restrict__ qkv) {
    int idx = blockIdx.x * 256 + threadIdx.x;   // 4096*16*64
    int i = idx & 63;
    int hh = (idx >> 6) & 15;
    int row = idx >> 10;
    int t = row & (TSEQ - 1);
    f16* base = qkv + (size_t)row * LDQKV + hh * HD;
    float inv = __expf((float)i * -0.14391156831f);  // ln(10000)/64
    float ang = (float)t * inv;
    float s, c;
    sincosf(ang, &s, &c);
    float x1 = (float)base[i], x2 = (float)base[i + 64];
    base[i]      = (f16)(x1 * c - x2 * s);
    base[i + 64] = (f16)(x2 * c + x1 * s);
}

// ------------- K repack: rope + swizzled [z][t][128] contiguous -------------
__global__ __launch_bounds__(256) void repack_k(const f16* __restrict__ qkv,
                                                f16* __restrict__ kpack) {
    int idx = blockIdx.x * 256 + threadIdx.x;   // 4096*4*64
    int i = idx & 63;
    int kvh = (idx >> 6) & 3;
    int row = idx >> 8;
    int t = row & (TSEQ - 1);
    int b = row >> 11;
    const f16* src = qkv + (size_t)row * LDQKV + DMODEL + kvh * HD;
    float inv = __expf((float)i * -0.14391156831f);
    float ang = (float)t * inv;
    float s, c;
    sincosf(ang, &s, &c);
    float x1 = (float)src[i], x2 = (float)src[i + 64];
    float r1 = x1 * c - x2 * s, r2 = x2 * c + x1 * s;
    f16* dst = kpack + ((size_t)((b * NKVH + kvh) * TSEQ + t)) * HD;
    int sw = t & 15;
    int i2 = i + 64;
    dst[(((i  >> 3) ^ sw) << 3) + (i  & 7)] = (f16)r1;
    dst[(((i2 >> 3) ^ sw) << 3) + (i2 & 7)] = (f16)r2;
}

// ------- V repack: [z][chunk][d][64] tiles (16 KB contiguous), swizzled -----
__global__ __launch_bounds__(256) void repack_v(const f16* __restrict__ qkv,
                                                f16* __restrict__ vpack) {
    int z = blockIdx.x >> 5;
    int c = blockIdx.x & 31;
    int b = z >> 2, kvh = z & 3;
    __shared__ f16 tile[64][136];
    int tr = threadIdx.x >> 4;
    int tcol = (threadIdx.x & 15) * 8;
    const f16* src = qkv + (size_t)(b * TSEQ + c * 64) * LDQKV + 2560 + kvh * HD;
#pragma unroll
    for (int i = 0; i < 4; ++i) {
        int row = i * 16 + tr;
        *(half8*)&tile[row][tcol] = *(const half8*)(src + (size_t)row * LDQKV + tcol);
    }
    __syncthreads();
    int d = threadIdx.x >> 1, hf = threadIdx.x & 1;
    f16* dst = vpack + ((size_t)z * 32 + c) * 8192 + d * 64;
#pragma unroll
    for (int j8 = 0; j8 < 4; ++j8) {
        int blk = hf * 4 + j8;
        half8 v;
#pragma unroll
        for (int e = 0; e < 8; ++e) v[e] = tile[blk * 8 + e][d];
        *(half8*)(dst + ((blk ^ (d & 7)) << 3)) = v;
    }
}

// ---------------- flash attention v3: LDS-staged, double-buffered -----------
__global__ __launch_bounds__(256) void flash_attn(const f16* __restrict__ qkv,
                                                  const f16* __restrict__ kpack,
                                                  const f16* __restrict__ vpack,
                                                  f16* __restrict__ out) {
    const int L = blockIdx.x;
    const int tt = L & 255;
    const int h = tt >> 4;
    const int qi = tt & 15;
    const int b = L >> 8;
    const int qt = b ? qi : (15 - qi);   // LPT pairing: L and L+256 complement
    const int q0 = qt * 128;
    const int w = threadIdx.x >> 6, lane = threadIdx.x & 63;
    const int cl = lane & 15, quad = lane >> 4;
    const int kvh = h >> 2;
    const int z = b * NKVH + kvh;
    const int qw = q0 + w * 32;

    __shared__ __align__(16) f16 Ks[2][64 * 128];
    __shared__ __align__(16) f16 Vs[2][64 * 128];
    __shared__ __align__(16) f16 Psh[4][32 * 64];
    f16* P = Psh[w];

    const f16* Q  = qkv + (size_t)(b * TSEQ) * LDQKV + h * HD;
    const f16* Kg = kpack + (size_t)z * (TSEQ * HD);
    const f16* Vg = vpack + (size_t)z * (32 * 8192);

    half8 qf[2][4];
#pragma unroll
    for (int mt = 0; mt < 2; ++mt)
#pragma unroll
        for (int ks = 0; ks < 4; ++ks)
            qf[mt][ks] = *(const half8*)(Q + (size_t)(qw + mt * 16 + cl) * LDQKV
                                         + ks * 32 + quad * 8);

    float m_[8], l_[8];
#pragma unroll
    for (int i = 0; i < 8; ++i) { m_[i] = -1e30f; l_[i] = 0.f; }
    const floatx4 fzero = {0.f, 0.f, 0.f, 0.f};
    floatx4 o[2][8];
#pragma unroll
    for (int mt = 0; mt < 2; ++mt)
#pragma unroll
        for (int nt = 0; nt < 8; ++nt) o[mt][nt] = fzero;

    const float scale = 0.088388347648318447f * 1.4426950408889634f;
    const int nblk   = ((q0 + 127) >> 6) + 1;
    const int nfullw = (qw + 1) >> 6;
    const int nstopw = ((qw + 31) >> 6) + 1;

    const int po = w * 512 + lane * 8;   // per-lane element offset for staging
    const int bo = w * 512;              // wave-uniform LDS element offset

#pragma unroll
    for (int r = 0; r < 4; ++r) {
        GLOAD_LDS(Kg + r * 2048 + po, Ks[0] + r * 2048 + bo);
        GLOAD_LDS(Vg + r * 2048 + po, Vs[0] + r * 2048 + bo);
    }
    __syncthreads();

    for (int c = 0; c < nblk; ++c) {
        const int buf = c & 1;
        if (c + 1 < nblk) {
            const f16* gk = Kg + (size_t)(c + 1) * 8192;
            const f16* gv = Vg + (size_t)(c + 1) * 8192;
            f16* sk = Ks[buf ^ 1];
            f16* sv = Vs[buf ^ 1];
#pragma unroll
            for (int r = 0; r < 4; ++r) {
                GLOAD_LDS(gk + r * 2048 + po, sk + r * 2048 + bo);
                GLOAD_LDS(gv + r * 2048 + po, sv + r * 2048 + bo);
            }
        }
        if (c < nstopw) {
            const int kb = c * 64;
            const bool masked = (c >= nfullw);
            const f16* KL = Ks[buf];
            const f16* VL = Vs[buf];

            floatx4 s[2][4];
#pragma unroll
            for (int mt = 0; mt < 2; ++mt)
#pragma unroll
                for (int nt = 0; nt < 4; ++nt) s[mt][nt] = fzero;
#pragma unroll
            for (int ks = 0; ks < 4; ++ks) {
                half8 kf[4];
#pragma unroll
                for (int nt = 0; nt < 4; ++nt) {
                    int r = nt * 16 + cl;
                    kf[nt] = *(const half8*)&KL[r * 128 + (((ks * 4 + quad) ^ (r & 15)) << 3)];
                }
#pragma unroll
                for (int mt = 0; mt < 2; ++mt)
#pragma unroll
                    for (int nt = 0; nt < 4; ++nt)
                        s[mt][nt] = __builtin_amdgcn_mfma_f32_16x16x32_f16(qf[mt][ks], kf[nt],
                                                                           s[mt][nt], 0, 0, 0);
            }

#pragma unroll
            for (int mt = 0; mt < 2; ++mt)
#pragma unroll
                for (int r = 0; r < 4; ++r) {
                    const int i8 = mt * 4 + r;
                    const int row = qw + mt * 16 + quad * 4 + r;
                    float v[4];
#pragma unroll
                    for (int nt = 0; nt < 4; ++nt) {
                        v[nt] = s[mt][nt][r] * scale;
                        if (masked) {
                            int col = kb + nt * 16 + cl;
                            if (col > row) v[nt] = -1e30f;
                        }
                    }
                    float mx = fmaxf(fmaxf(v[0], v[1]), fmaxf(v[2], v[3]));
#pragma unroll
                    for (int off = 1; off < 16; off <<= 1) mx = fmaxf(mx, __shfl_xor(mx, off, 64));
                    float mnew = fmaxf(m_[i8], mx);
                    float alpha = exp2f(m_[i8] - mnew);
                    float p[4];
#pragma unroll
                    for (int nt = 0; nt < 4; ++nt) p[nt] = exp2f(v[nt] - mnew);
                    float rs = (p[0] + p[1]) + (p[2] + p[3]);
#pragma unroll
                    for (int off = 1; off < 16; off <<= 1) rs += __shfl_xor(rs, off, 64);
                    l_[i8] = l_[i8] * alpha + rs;
                    m_[i8] = mnew;
#pragma unroll
                    for (int nt = 0; nt < 8; ++nt) o[mt][nt][r] *= alpha;
                    const int pr = mt * 16 + quad * 4 + r;
#pragma unroll
                    for (int nt = 0; nt < 4; ++nt) {
                        int col = nt * 16 + cl;
                        int cs = ((((col >> 3) ^ (pr & 7)) << 3) | (col & 7));
                        P[pr * 64 + cs] = (f16)p[nt];
                    }
                }

#pragma unroll
            for (int kk = 0; kk < 2; ++kk) {
                half8 pf[2];
#pragma unroll
                for (int mt = 0; mt < 2; ++mt) {
                    int pr = mt * 16 + cl;
                    int cb = kk * 4 + quad;
                    pf[mt] = *(const half8*)&P[pr * 64 + ((cb ^ (pr & 7)) << 3)];
                }
#pragma unroll
                for (int nt = 0; nt < 8; ++nt) {
                    int r = nt * 16 + cl;
                    half8 vv = *(const half8*)&VL[r * 64 + (((kk * 4 + quad) ^ (r & 7)) << 3)];
#pragma unroll
                    for (int mt = 0; mt < 2; ++mt)
                        o[mt][nt] = __builtin_amdgcn_mfma_f32_16x16x32_f16(pf[mt], vv,
                                                                           o[mt][nt], 0, 0, 0);
                }
            }
        }
        __syncthreads();
    }

    f16* Op = out + (size_t)(b * TSEQ + qw) * DMODEL + h * HD;
#pragma unroll
    for (int mt = 0; mt < 2; ++mt)
#pragma unroll
        for (int r = 0; r < 4; ++r) {
            float invl = 1.0f / l_[mt * 4 + r];
#pragma unroll
            for (int nt = 0; nt < 8; ++nt)
                Op[(size_t)(mt * 16 + quad * 4 + r) * DMODEL + nt * 16 + cl] =
                    (f16)(o[mt][nt][r] * invl);
        }
}

// ---------------- SwiGLU: gu[:, :5632] = silu(gate) * up (in place) ---------
__global__ __launch_bounds__(256) void silu_mul(f16* __restrict__ gu) {
    int idx = blockIdx.x * 256 + threadIdx.x;  // 4096 * 704
    int row = idx / 704;
    int j = (idx - row * 704) * 8;
    size_t base = (size_t)row * LDGU;
    half8 g = *(half8*)(gu + base + j);
    half8 u = *(half8*)(gu + base + INTERDIM + j);
    half8 o;
#pragma unroll
    for (int e = 0; e < 8; ++e) {
        float gv = (float)g[e], uv = (float)u[e];
        float sg = gv / (1.f + __expf(-gv));
        o[e] = (f16)(sg * uv);
    }
    *(half8*)(gu + base + j) = o;
}

extern "C" void kernel_launch(void* const* d_in, const int* in_sizes, int n_in,
                              void* d_out, int out_size, void* d_ws, size_t ws_size,
                              hipStream_t stream) {
    const float* x   = (const float*)d_in[0];
    const float* ln1 = (const float*)d_in[1];
    const float* ln2 = (const float*)d_in[2];
    const float* wq  = (const float*)d_in[3];
    const float* wk  = (const float*)d_in[4];
    const float* wv  = (const float*)d_in[5];
    const float* wo  = (const float*)d_in[6];
    const float* wg  = (const float*)d_in[7];
    const float* wu  = (const float*)d_in[8];
    const float* wd  = (const float*)d_in[9];
    float* out = (float*)d_out;

    char* p = (char*)d_ws;
    f16* wqkv_h = (f16*)p; p += (size_t)3072 * 2048 * 2;
    f16* wo_h   = (f16*)p; p += (size_t)2048 * 2048 * 2;
    f16* wgu_h  = (f16*)p; p += (size_t)11264 * 2048 * 2;
    f16* wd_h   = (f16*)p; p += (size_t)2048 * 5632 * 2;
    f16* h_h    = (f16*)p; p += (size_t)4096 * 2048 * 2;  // later reused as attn-out
    f16* qkv_h  = (f16*)p; p += (size_t)4096 * 3072 * 2;  // later reused as h2
    f16* kpack  = (f16*)p; p += (size_t)8 * 2048 * 128 * 2;
    f16* vpack  = (f16*)p; p += (size_t)8 * 32 * 8192 * 2;
    f16* gu_h   = (f16*)p;                                 // 4096*11264*2

    cast_all<<<44032, 256, 0, stream>>>(wq, wk, wv, wo, wg, wu, wd,
                                        wqkv_h, wo_h, wgu_h, wd_h);

    rmsnorm_kernel<<<4096, 256, 0, stream>>>(x, ln1, h_h);
    // QKV projection (fused N = 2048+512+512 = 3072)
    gemm_bt<<<24 * 32, 256, 0, stream>>>(h_h, 2048, wqkv_h, 2048,
                                         qkv_h, nullptr, nullptr, 3072, 2048, 24);
    rope_q<<<16384, 256, 0, stream>>>(qkv_h);
    repack_k<<<4096, 256, 0, stream>>>(qkv_h, kpack);
    repack_v<<<256, 256, 0, stream>>>(qkv_h, vpack);
    flash_attn<<<512, 256, 0, stream>>>(qkv_h, kpack, vpack, h_h);
    // out = x + attn @ wo^T   (fp32 residual into d_out)
    gemm_bt<<<16 * 32, 256, 0, stream>>>(h_h, 2048, wo_h, 2048,
                                         nullptr, out, x, 2048, 2048, 16);
    rmsnorm_kernel<<<4096, 256, 0, stream>>>(out, ln2, qkv_h);  // h2 in qkv buffer
    // gate|up (fused N = 11264)
    gemm_bt<<<88 * 32, 256, 0, stream>>>(qkv_h, 2048, wgu_h, 2048,
                                         gu_h, nullptr, nullptr, 11264, 2048, 88);
    silu_mul<<<11264, 256, 0, stream>>>(gu_h);
    // out += mid @ wd^T
    gemm_bt<<<16 * 32, 256, 0, stream>>>(gu_h, 11264, wd_h, 5632,
                                         nullptr, out, out, 2048, 5632, 16);
}